// Round 3
// baseline (382.274 us; speedup 1.0000x reference)
//
#include <hip/hip_runtime.h>
#include <hip/hip_bf16.h>
#include <math.h>

#define NB 2
#define LL 64
#define NMESH 100000
#define HEADS_O 8
#define DHC 64
#define DMODEL 512
#define DINNER 1024
#define DSTATE 64
#define NH 16
#define CONVDIM 1152
#define DINPROJ 2208
#define DOUT 256

typedef __attribute__((ext_vector_type(8))) short short8v;   // 8 x bf16
typedef __attribute__((ext_vector_type(4))) float f32x4;

__device__ __forceinline__ unsigned short f2bf(float f) {
  union { float f; unsigned u; } v; v.f = f;
  unsigned u = v.u;
  u += 0x7FFFu + ((u >> 16) & 1u);
  return (unsigned short)(u >> 16);
}

__device__ __forceinline__ float dot4(float4 a, const float* b) {
  return a.x*b[0] + a.y*b[1] + a.z*b[2] + a.w*b[3];
}

// ---------------------------------------------------------------- K1: in_proj (weight-streaming)
// zx[bl,o] = sum_m u[bl,m] * w[o,m]; 4 bl-rows staged in LDS, broadcast.
__global__ void k_inproj(const float* __restrict__ st, const float* __restrict__ w,
                         float* __restrict__ zx) {
  int oc = blockIdx.x;             // 0..8 : o = oc*256 + t
  int blc = blockIdx.y;            // 0..31: bl = blc*4 + r
  int t = threadIdx.x;
  __shared__ float u[4][DMODEL];   // 8 KB
  for (int idx = t; idx < 4*DMODEL; idx += 256) {
    int r = idx >> 9, m = idx & 511;
    int bl = blc*4 + r; int b = bl >> 6, l = bl & 63;
    u[r][m] = st[((size_t)(b*HEADS_O + (m >> 6))*LL + l)*DHC + (m & 63)];
  }
  __syncthreads();
  int o = oc*256 + t;
  if (o < DINPROJ) {
    const float4* wr = (const float4*)(w + (size_t)o*DMODEL);
    float acc[4] = {0,0,0,0};
    for (int m4 = 0; m4 < DMODEL/4; ++m4) {
      float4 wv = wr[m4];
      #pragma unroll
      for (int r = 0; r < 4; ++r) acc[r] += dot4(wv, &u[r][m4*4]);
    }
    #pragma unroll
    for (int r = 0; r < 4; ++r)
      zx[(size_t)(blc*4 + r)*DINPROJ + o] = acc[r];
  }
}

// ---------------------------------------------------------------- K2: fused depthwise conv+silu AND dt softplus
__global__ void k_convdt(const float* __restrict__ zx, const float* __restrict__ cw,
                         const float* __restrict__ cb, const float* __restrict__ dtb,
                         float* __restrict__ conv_out, float* __restrict__ dtbuf) {
  if (blockIdx.x < 576) {
    int i = blockIdx.x*256 + threadIdx.x;           // < 147456
    int c = i % CONVDIM; int l = (i / CONVDIM) % LL; int b = i / (CONVDIM*LL);
    float s = cb[c];
    #pragma unroll
    for (int k = 0; k < 3; ++k) {
      int tt = l - 1 + k;
      if (tt >= 0 && tt < LL)
        s += cw[c*3 + k] * zx[(size_t)(b*LL + tt)*DINPROJ + DINNER + c];
    }
    conv_out[i] = s / (1.f + expf(-s));
  } else {
    int i = (blockIdx.x - 576)*256 + threadIdx.x;   // (s*64+l)*16+h, 4096 total
    if (i < 4*LL*NH) {
      int h = i & 15, l = (i >> 4) & 63, s = i >> 10;
      float v;
      if (s < 2)
        v = zx[(size_t)(s*LL + l)*DINPROJ + (DINNER + CONVDIM) + h];
      else
        v = zx[(size_t)((s-2)*LL + (63-l))*DINPROJ + (DINNER + CONVDIM) + 16 + h];
      v += dtb[h];
      dtbuf[i] = (v > 20.f) ? v : log1pf(expf(v));
    }
  }
}

// ---------------------------------------------------------------- K4: SSD scan (parallel form)
__global__ void k_scan(const float* __restrict__ conv_out, const float* __restrict__ dtbuf,
                       const float* __restrict__ A_log, float* __restrict__ ybuf) {
  int blk = blockIdx.x;
  int s = blk >> 4, hh = blk & 15;
  int b = s & 1;
  bool rev = (s >= 2);
  int t = threadIdx.x;
  int wv = t >> 6, lane = t & 63;
  __shared__ float Bs[64*68];
  __shared__ float Cs[64*68];
  __shared__ float Xs[64*64];
  __shared__ float dts[64];
  __shared__ float Dc[64];

  for (int id = t; id < 4096; id += 256) {
    int tt0 = id >> 6, n = id & 63;
    int tt = rev ? (63 - tt0) : tt0;
    size_t base = (size_t)(b*LL + tt) * CONVDIM;
    Xs[tt0*64 + n] = conv_out[base + hh*64 + n];
    Bs[tt0*68 + n] = conv_out[base + DINNER + n];
    Cs[tt0*68 + n] = conv_out[base + DINNER + DSTATE + n];
  }
  if (t < 64) dts[t] = dtbuf[(size_t)(s*LL + t)*NH + hh];
  __syncthreads();
  if (t < 64) {
    float v = dts[t];
    #pragma unroll
    for (int m = 1; m < 64; m <<= 1) {
      float o = __shfl_up(v, m, 64);
      if (lane >= m) v += o;
    }
    Dc[t] = v;
  }
  __syncthreads();
  float A = -expf(A_log[hh]);
  float g[16];
  #pragma unroll
  for (int i = 0; i < 16; ++i) {
    int tt = wv + 4*i;
    int ta = lane;
    float gv = 0.f;
    if (ta <= tt) {
      const float* Br = &Bs[ta*68];
      const float* Cr = &Cs[tt*68];
      float dot = 0.f;
      #pragma unroll
      for (int n4 = 0; n4 < 16; ++n4) {
        float4 bv = *(const float4*)&Br[n4*4];
        float4 cv = *(const float4*)&Cr[n4*4];
        dot += bv.x*cv.x + bv.y*cv.y + bv.z*cv.z + bv.w*cv.w;
      }
      gv = dot * expf(A * (Dc[tt] - Dc[ta])) * dts[ta];
    }
    g[i] = gv;
  }
  __syncthreads();
  #pragma unroll
  for (int i = 0; i < 16; ++i) Bs[(wv + 4*i)*64 + lane] = g[i];
  __syncthreads();
  for (int id = t; id < 4096; id += 256) {
    int tt = id >> 6, p = id & 63;
    float y = 0.f;
    for (int ta = 0; ta <= tt; ++ta) y += Bs[tt*64 + ta] * Xs[ta*64 + p];
    ybuf[(size_t)(s*LL + tt)*DINNER + hh*64 + p] = y;
  }
}

// ---------------------------------------------------------------- K5a: combine + gate + RMSnorm -> ynorm
__global__ void k_combine_a(const float* __restrict__ conv_out, const float* __restrict__ zx,
                            const float* __restrict__ yb, const float* __restrict__ fcD,
                            const float* __restrict__ Dd, const float* __restrict__ nw,
                            float* __restrict__ ynorm) {
  int bl = blockIdx.x; int b = bl >> 6, l = bl & 63;
  int t = threadIdx.x;
  __shared__ float xog[DINNER];
  __shared__ float diag[NH];
  __shared__ float wsum[4];
  size_t base = (size_t)bl * CONVDIM;
  for (int c = t; c < DINNER; c += 256) xog[c] = conv_out[base + c];
  __syncthreads();
  {
    int hh = t >> 4, j = t & 15;
    const float* fr = fcD + (size_t)hh*DINNER;
    float acc = 0.f;
    for (int k = 0; k < 64; ++k) acc += xog[j + 16*k] * fr[j + 16*k];
    #pragma unroll
    for (int m = 8; m >= 1; m >>= 1) acc += __shfl_xor(acc, m, 64);
    if (j == 0) diag[hh] = acc + Dd[hh];
  }
  __syncthreads();
  float ss = 0.f;
  float y2v[4];
  #pragma unroll
  for (int i = 0; i < 4; ++i) {
    int c = t + 256*i;
    float yf = (l == 0)  ? 0.f : yb[(size_t)(b*LL + l - 1)*DINNER + c];
    float yw = (l == 63) ? 0.f : yb[(size_t)((2+b)*LL + 62 - l)*DINNER + c];
    float y1 = yf + yw + xog[c]*diag[c >> 6];
    float z = zx[(size_t)bl*DINPROJ + c];
    float y2 = y1 * (z / (1.f + expf(-z)));
    y2v[i] = y2;
    ss += y2*y2;
  }
  #pragma unroll
  for (int m = 32; m >= 1; m >>= 1) ss += __shfl_xor(ss, m, 64);
  if ((t & 63) == 0) wsum[t >> 6] = ss;
  __syncthreads();
  float tot = wsum[0] + wsum[1] + wsum[2] + wsum[3];
  float scale = rsqrtf(tot * (1.f/1024.f) + 1e-5f);
  #pragma unroll
  for (int i = 0; i < 4; ++i) {
    int c = t + 256*i;
    ynorm[(size_t)bl*DINNER + c] = y2v[i] * scale * nw[c];
  }
}

// ---------------------------------------------------------------- K5b: out_proj (weight-streaming)
__global__ void k_oproj(const float* __restrict__ ynorm, const float* __restrict__ opw,
                        float* __restrict__ oh) {
  int oc = blockIdx.x;            // 0..1 : o = oc*256 + t
  int blc = blockIdx.y;           // 0..31: bl = blc*4 + r
  int t = threadIdx.x;
  __shared__ float yr[4][DINNER]; // 16 KB
  for (int idx = t; idx < 4*DINNER; idx += 256) {
    int r = idx >> 10, k = idx & 1023;
    yr[r][k] = ynorm[(size_t)(blc*4 + r)*DINNER + k];
  }
  __syncthreads();
  int o = oc*256 + t;
  const float4* wr = (const float4*)(opw + (size_t)o*DINNER);
  float acc[4] = {0,0,0,0};
  for (int k4 = 0; k4 < DINNER/4; ++k4) {
    float4 wv = wr[k4];
    #pragma unroll
    for (int r = 0; r < 4; ++r) acc[r] += dot4(wv, &yr[r][k4*4]);
  }
  #pragma unroll
  for (int r = 0; r < 4; ++r)
    oh[(size_t)(blc*4 + r)*DMODEL + o] = acc[r];
}

// ---------------------------------------------------------------- K6: build M in B-fragment order (bf16)
// M[b,h,g,d] = sum_c oh[b,g,h*64+c] * tow[d,h*64+c]
__global__ void k_mfrag(const float* __restrict__ oh, const float* __restrict__ tow,
                        unsigned short* __restrict__ mfp) {
  int bgc = blockIdx.x;            // 0..15, bg = bgc*8 + r
  int dc  = blockIdx.y;            // 0..3 : d = dc*64 + dl
  int t = threadIdx.x;
  __shared__ float orow[8][DMODEL]; // 16 KB
  for (int idx = t; idx < 8*DMODEL; idx += 256) {
    int r = idx >> 9, m = idx & 511;
    orow[r][m] = oh[(size_t)(bgc*8 + r)*DMODEL + m];
  }
  __syncthreads();
  #pragma unroll
  for (int ii = 0; ii < 2; ++ii) {
    int idx = t + 256*ii;          // 0..511 -> (h, dl)
    int h = idx >> 6, dl = idx & 63;
    int d = dc*64 + dl;
    const float4* wr = (const float4*)(tow + (size_t)d*DMODEL + h*64);
    float acc[8] = {0,0,0,0,0,0,0,0};
    #pragma unroll
    for (int c4 = 0; c4 < 16; ++c4) {
      float4 wv = wr[c4];
      #pragma unroll
      for (int r = 0; r < 8; ++r) acc[r] += dot4(wv, &orow[r][h*64 + c4*4]);
    }
    #pragma unroll
    for (int r = 0; r < 8; ++r) {
      int bg = bgc*8 + r; int b = bg >> 6, g = bg & 63;
      int kk = g >> 5;
      int ln = (d & 15) | (((g & 31) >> 3) << 4);
      int j = g & 7;
      mfp[((((size_t)(b*HEADS_O + h)*2 + kk)*16 + (d >> 4))*64 + ln)*8 + j] = f2bf(acc[r]);
    }
  }
}

// ---------------------------------------------------------------- K7: big GEMM, barrier-free streaming
// out[b,n,d] = sum_{h,g} W[b,h,n,g]*M[b,h,g,d] + tob[d]
// Block: 64 rows x 256 cols. Wave wv owns cols [wv*64, wv*64+64) (4 ct tiles),
// 4 row-tiles of 16. B fragments read directly from L2-resident mf.
// A+B register-double-buffered 2 stages deep. No LDS, no barriers.
__global__ __launch_bounds__(256, 2) void k_out_gemm(const float* __restrict__ W,
                                                     const unsigned short* __restrict__ mf,
                                                     const float* __restrict__ tob,
                                                     float* __restrict__ out) {
  int b = blockIdx.y;
  int n0 = blockIdx.x * 64;
  int tid = threadIdx.x;
  int wv = tid >> 6, lane = tid & 63;
  int r16 = lane & 15, kg = lane >> 4;

  const float* abase[4];
  #pragma unroll
  for (int rt = 0; rt < 4; ++rt) {
    int r = n0 + rt*16 + r16;
    int rc = r < NMESH ? r : NMESH - 1;
    abase[rt] = W + ((size_t)b*HEADS_O*NMESH + rc)*64 + kg*8;
  }
  // B frag (stage s, local tile j): mf[(b*256 + s*16 + wv*4 + j)*512 + lane*8]
  const unsigned short* bb = mf + ((size_t)b*256 + wv*4)*512 + lane*8;

  f32x4 acc[4][4];
  #pragma unroll
  for (int i = 0; i < 4; ++i)
    #pragma unroll
    for (int j = 0; j < 4; ++j) acc[i][j] = (f32x4){0,0,0,0};

  float4 a0[2][4], a1[2][4]; short8v bn[2][4];
  // prologue: stages 0 and 1
  #pragma unroll
  for (int p = 0; p < 2; ++p) {
    size_t aoff = (size_t)(p >> 1)*NMESH*64 + (size_t)(p & 1)*32;
    #pragma unroll
    for (int rt = 0; rt < 4; ++rt) {
      a0[p][rt] = *(const float4*)(abase[rt] + aoff);
      a1[p][rt] = *(const float4*)(abase[rt] + aoff + 4);
    }
    const unsigned short* bs = bb + (size_t)p*8192;
    #pragma unroll
    for (int j = 0; j < 4; ++j) bn[p][j] = *(const short8v*)(bs + j*512);
  }

  #pragma unroll
  for (int s = 0; s < 16; ++s) {
    const int p = s & 1;
    // convert current A (forces wait on stage-s loads, issued 2 stages ago)
    short8v af[4];
    #pragma unroll
    for (int rt = 0; rt < 4; ++rt) {
      af[rt][0] = (short)f2bf(a0[p][rt].x); af[rt][1] = (short)f2bf(a0[p][rt].y);
      af[rt][2] = (short)f2bf(a0[p][rt].z); af[rt][3] = (short)f2bf(a0[p][rt].w);
      af[rt][4] = (short)f2bf(a1[p][rt].x); af[rt][5] = (short)f2bf(a1[p][rt].y);
      af[rt][6] = (short)f2bf(a1[p][rt].z); af[rt][7] = (short)f2bf(a1[p][rt].w);
    }
    short8v cb[4];
    #pragma unroll
    for (int j = 0; j < 4; ++j) cb[j] = bn[p][j];
    if (s < 14) {   // issue loads for stage s+2 into slot p
      int s2 = s + 2;
      size_t aoff = (size_t)(s2 >> 1)*NMESH*64 + (size_t)(s2 & 1)*32;
      #pragma unroll
      for (int rt = 0; rt < 4; ++rt) {
        a0[p][rt] = *(const float4*)(abase[rt] + aoff);
        a1[p][rt] = *(const float4*)(abase[rt] + aoff + 4);
      }
      const unsigned short* bs = bb + (size_t)s2*8192;
      #pragma unroll
      for (int j = 0; j < 4; ++j) bn[p][j] = *(const short8v*)(bs + j*512);
    }
    #pragma unroll
    for (int rt = 0; rt < 4; ++rt)
      #pragma unroll
      for (int j = 0; j < 4; ++j)
        acc[rt][j] = __builtin_amdgcn_mfma_f32_16x16x32_bf16(af[rt], cb[j], acc[rt][j], 0, 0, 0);
  }

  // epilogue: C layout col=lane&15, row=(lane>>4)*4+r
  #pragma unroll
  for (int rt = 0; rt < 4; ++rt) {
    int rb = n0 + rt*16 + kg*4;
    #pragma unroll
    for (int j = 0; j < 4; ++j) {
      int colg = (wv*4 + j)*16 + r16;
      float bias = tob[colg];
      #pragma unroll
      for (int r = 0; r < 4; ++r) {
        int rr = rb + r;
        if (rr < NMESH)
          out[((size_t)b*NMESH + rr)*DOUT + colg] = acc[rt][j][r] + bias;
      }
    }
  }
}

// ----------------------------------------------------------------
extern "C" void kernel_launch(void* const* d_in, const int* in_sizes, int n_in,
                              void* d_out, int out_size, void* d_ws, size_t ws_size,
                              hipStream_t stream) {
  (void)in_sizes; (void)n_in; (void)out_size; (void)ws_size;
  const float* st   = (const float*)d_in[0];
  const float* sw   = (const float*)d_in[1];
  const float* ipw  = (const float*)d_in[2];
  const float* cw   = (const float*)d_in[3];
  const float* cb   = (const float*)d_in[4];
  const float* dtb  = (const float*)d_in[5];
  const float* alog = (const float*)d_in[6];
  const float* fcD  = (const float*)d_in[7];
  const float* Dd   = (const float*)d_in[8];
  const float* nw   = (const float*)d_in[9];
  const float* opw  = (const float*)d_in[10];
  const float* tow  = (const float*)d_in[11];
  const float* tob  = (const float*)d_in[12];
  float* out = (float*)d_out;
  unsigned char* ws = (unsigned char*)d_ws;

  float* zx   = (float*)(ws + 0);            // 2*64*2208*4   = 1130496
  float* conv = (float*)(ws + 1130496);      // 2*64*1152*4   = 589824
  float* dtp  = (float*)(ws + 1720320);      // 4*64*16*4     = 16384
  float* yb   = (float*)(ws + 1736704);      // 4*64*1024*4   = 1048576
  float* oh   = (float*)(ws + 2785280);      // 2*64*512*4    = 262144
  unsigned short* mfr = (unsigned short*)(ws + 3047424); // 524288
  float* ynm  = (float*)(ws + 3571712);      // 2*64*1024*4   = 524288

  k_inproj   <<<dim3(9, 32), 256, 0, stream>>>(st, ipw, zx);
  k_convdt   <<<592, 256, 0, stream>>>(zx, cw, cb, dtb, conv, dtp);
  k_scan     <<<64,  256, 0, stream>>>(conv, dtp, alog, yb);
  k_combine_a<<<128, 256, 0, stream>>>(conv, zx, yb, fcD, Dd, nw, ynm);
  k_oproj    <<<dim3(2, 32), 256, 0, stream>>>(ynm, opw, oh);
  k_mfrag    <<<dim3(16, 4), 256, 0, stream>>>(oh, tow, mfr);
  k_out_gemm <<<dim3((NMESH + 63)/64, NB), 256, 0, stream>>>(sw, mfr, tob, out);
}